// Round 1
// baseline (4981.174 us; speedup 1.0000x reference)
//
#include <hip/hip_runtime.h>
#include <hip/hip_bf16.h>

#define NN 100000
#define DIN 128
#define DOUT 256
#define RR 4
#define EE 600000

// ---------------- weight prep ----------------
// in: [nsum][O][K] (stride sumstride between r), out[k][o] = sum_r in[r][o][k]
__global__ void transpose_sum(const float* __restrict__ in, float* __restrict__ out,
                              int K, int O, int nsum, long sumstride) {
    int idx = blockIdx.x * blockDim.x + threadIdx.x;
    if (idx >= K * O) return;
    int k = idx / O, o = idx % O;
    float s = 0.f;
    for (int r = 0; r < nsum; ++r) s += in[r * sumstride + (long)o * K + k];
    out[(long)k * O + o] = s;
}

__global__ void bias_sum(const float* __restrict__ b, float* __restrict__ bs, int O, int nr) {
    int o = blockIdx.x * blockDim.x + threadIdx.x;
    if (o >= O) return;
    float s = 0.f;
    for (int r = 0; r < nr; ++r) s += b[(long)r * O + o];
    bs[o] = s;
}

// ---------------- scatter-add aggregation ----------------
template <int D>
__global__ void scatter_add(const float* __restrict__ feat,
                            const int* __restrict__ esrc, const int* __restrict__ edst,
                            float* __restrict__ agg, int nE) {
    long gt = (long)blockIdx.x * blockDim.x + threadIdx.x;
    long total = (long)nE * D;
    if (gt >= total) return;
    int e = (int)(gt / D);
    int d = (int)(gt % D);
    int s = esrc[e];
    int t = edst[e];
    atomicAdd(&agg[(long)t * D + d], feat[(long)s * D + d]);
}

// ---------------- tiled fp32 GEMM: C[n,o] (+)= scale*(dot(A[n,:],Wt[:,o]) + bias[o]) ----------------
// A: [M,K] row-major, Wt: [K,256], C: [M,256]. Block: 64 rows x 256 cols, 256 threads.
// Thread = (ct 0..63, rg 0..3): computes rows rg*16..rg*16+15, cols ct+{0,64,128,192}.
#define GBM 64
#define GBK 32
__global__ __launch_bounds__(256) void gemm_acc(
    const float* __restrict__ A, int K, const float* __restrict__ Wt,
    const float* __restrict__ bias, float* __restrict__ C,
    int M, float scale, int accum) {
    __shared__ float a_lds[GBM][GBK + 1];
    int n0 = blockIdx.x * GBM;
    int tid = threadIdx.x;
    int ct = tid & 63;
    int rg = tid >> 6;

    float acc[16][4];
#pragma unroll
    for (int i = 0; i < 16; ++i)
#pragma unroll
        for (int j = 0; j < 4; ++j) acc[i][j] = 0.f;

    int rr = tid >> 2;          // 0..63
    int kk0 = (tid & 3) * 8;    // 0,8,16,24

    for (int k0 = 0; k0 < K; k0 += GBK) {
        float4 v0, v1;
        if (n0 + rr < M) {
            const float* ap = A + (size_t)(n0 + rr) * K + k0 + kk0;
            v0 = *(const float4*)ap;
            v1 = *(const float4*)(ap + 4);
        } else {
            v0 = make_float4(0.f, 0.f, 0.f, 0.f);
            v1 = v0;
        }
        __syncthreads();  // previous iteration's reads done before overwrite
        a_lds[rr][kk0 + 0] = v0.x; a_lds[rr][kk0 + 1] = v0.y;
        a_lds[rr][kk0 + 2] = v0.z; a_lds[rr][kk0 + 3] = v0.w;
        a_lds[rr][kk0 + 4] = v1.x; a_lds[rr][kk0 + 5] = v1.y;
        a_lds[rr][kk0 + 6] = v1.z; a_lds[rr][kk0 + 7] = v1.w;
        __syncthreads();

        for (int kk = 0; kk < GBK; ++kk) {
            const float* wrow = Wt + (size_t)(k0 + kk) * 256 + ct;
            float w0 = wrow[0];
            float w1 = wrow[64];
            float w2 = wrow[128];
            float w3 = wrow[192];
#pragma unroll
            for (int i = 0; i < 16; ++i) {
                float a = a_lds[rg * 16 + i][kk];
                acc[i][0] += a * w0;
                acc[i][1] += a * w1;
                acc[i][2] += a * w2;
                acc[i][3] += a * w3;
            }
        }
        __syncthreads();
    }

    int rbase = n0 + rg * 16;
#pragma unroll
    for (int i = 0; i < 16; ++i) {
        int n = rbase + i;
        if (n >= M) break;
#pragma unroll
        for (int j = 0; j < 4; ++j) {
            int o = ct + 64 * j;
            float v = acc[i][j];
            if (bias) v += bias[o];
            v *= scale;
            size_t idx = (size_t)n * 256 + o;
            if (accum) C[idx] += v;
            else C[idx] = v;
        }
    }
}

// ---------------- l2-normalize + relu, in place, one wave per row ----------------
__global__ void norm_relu(float* __restrict__ H, int M) {
    int row = blockIdx.x * 4 + (threadIdx.x >> 6);
    if (row >= M) return;
    int lane = threadIdx.x & 63;
    float4* p = (float4*)(H + (size_t)row * 256);
    float4 v = p[lane];
    float ss = v.x * v.x + v.y * v.y + v.z * v.z + v.w * v.w;
    for (int off = 1; off < 64; off <<= 1) ss += __shfl_xor(ss, off);
    float denom = fmaxf(sqrtf(ss), 1e-12f);
    float inv = 1.0f / denom;
    v.x = fmaxf(v.x * inv, 0.f);
    v.y = fmaxf(v.y * inv, 0.f);
    v.z = fmaxf(v.z * inv, 0.f);
    v.w = fmaxf(v.w * inv, 0.f);
    p[lane] = v;
}

extern "C" void kernel_launch(void* const* d_in, const int* in_sizes, int n_in,
                              void* d_out, int out_size, void* d_ws, size_t ws_size,
                              hipStream_t stream) {
    const float* x   = (const float*)d_in[0];
    const int*   ei  = (const int*)d_in[1];
    const float* W1n = (const float*)d_in[2];
    const float* b1  = (const float*)d_in[3];
    const float* W1r = (const float*)d_in[4];
    const float* W2n = (const float*)d_in[5];
    const float* b2  = (const float*)d_in[6];
    const float* W2r = (const float*)d_in[7];
    float* out = (float*)d_out;

    float* ws = (float*)d_ws;
    float* HBUF = ws;                                   // N*256 f32
    float* AGG  = HBUF + (size_t)NN * 256;              // N*256 f32
    float* w1n_t  = AGG + (size_t)NN * 256;             // 4*128*256
    float* w1rs_t = w1n_t + 4 * 128 * 256;              // 128*256
    float* w2n_t  = w1rs_t + 128 * 256;                 // 4*256*256
    float* w2rs_t = w2n_t + 4 * 256 * 256;              // 256*256
    float* b1s    = w2rs_t + 256 * 256;                 // 256
    float* b2s    = b1s + 256;                          // 256

    // ---- weight prep ----
    {
        int nw1 = 128 * 256, nw2 = 256 * 256;
        for (int r = 0; r < RR; ++r)
            transpose_sum<<<(nw1 + 255) / 256, 256, 0, stream>>>(
                W1n + (size_t)r * DOUT * DIN, w1n_t + (size_t)r * 128 * 256, 128, 256, 1, 0);
        transpose_sum<<<(nw1 + 255) / 256, 256, 0, stream>>>(
            W1r, w1rs_t, 128, 256, RR, (long)DOUT * DIN);
        for (int r = 0; r < RR; ++r)
            transpose_sum<<<(nw2 + 255) / 256, 256, 0, stream>>>(
                W2n + (size_t)r * DOUT * DOUT, w2n_t + (size_t)r * 256 * 256, 256, 256, 1, 0);
        transpose_sum<<<(nw2 + 255) / 256, 256, 0, stream>>>(
            W2r, w2rs_t, 256, 256, RR, (long)DOUT * DOUT);
        bias_sum<<<1, 256, 0, stream>>>(b1, b1s, 256, RR);
        bias_sum<<<1, 256, 0, stream>>>(b2, b2s, 256, RR);
    }

    int gemm_grid = (NN + GBM - 1) / GBM;
    const float scale = 1.0f / RR;

    // ---- layer 1 ----
    // x-path (writes H, adds summed bias)
    gemm_acc<<<gemm_grid, 256, 0, stream>>>(x, 128, w1rs_t, b1s, HBUF, NN, scale, 0);
    for (int r = 0; r < RR; ++r) {
        hipMemsetAsync(AGG, 0, (size_t)NN * 128 * sizeof(float), stream);
        const int* esrc = ei + (size_t)r * 2 * EE;
        const int* edst = esrc + EE;
        long total = (long)EE * 128;
        scatter_add<128><<<(int)((total + 255) / 256), 256, 0, stream>>>(x, esrc, edst, AGG, EE);
        gemm_acc<<<gemm_grid, 256, 0, stream>>>(AGG, 128, w1n_t + (size_t)r * 128 * 256,
                                                nullptr, HBUF, NN, scale, 1);
    }
    norm_relu<<<(NN + 3) / 4, 256, 0, stream>>>(HBUF, NN);

    // ---- layer 2 ----
    gemm_acc<<<gemm_grid, 256, 0, stream>>>(HBUF, 256, w2rs_t, b2s, out, NN, scale, 0);
    for (int r = 0; r < RR; ++r) {
        hipMemsetAsync(AGG, 0, (size_t)NN * 256 * sizeof(float), stream);
        const int* esrc = ei + (size_t)r * 2 * EE;
        const int* edst = esrc + EE;
        long total = (long)EE * 256;
        scatter_add<256><<<(int)((total + 255) / 256), 256, 0, stream>>>(HBUF, esrc, edst, AGG, EE);
        gemm_acc<<<gemm_grid, 256, 0, stream>>>(AGG, 256, w2n_t + (size_t)r * 256 * 256,
                                                nullptr, out, NN, scale, 1);
    }
}

// Round 2
// 3214.344 us; speedup vs baseline: 1.5497x; 1.5497x over previous
//
#include <hip/hip_runtime.h>
#include <hip/hip_bf16.h>

#define NN 100000
#define DIN 128
#define DOUT 256
#define RR 4
#define EE 600000
#define NB (RR * NN)   // CSR buckets: (relation, dst-node)

// ---------------- weight prep ----------------
// out[k][o] = sum_r in[r][o][k]  (in: [nsum][O][K], stride sumstride between r)
__global__ void transpose_sum(const float* __restrict__ in, float* __restrict__ out,
                              int K, int O, int nsum, long sumstride) {
    int idx = blockIdx.x * blockDim.x + threadIdx.x;
    if (idx >= K * O) return;
    int k = idx / O, o = idx % O;
    float s = 0.f;
    for (int r = 0; r < nsum; ++r) s += in[r * sumstride + (long)o * K + k];
    out[(long)k * O + o] = s;
}

__global__ void bias_sum(const float* __restrict__ b, float* __restrict__ bs, int O, int nr) {
    int o = blockIdx.x * blockDim.x + threadIdx.x;
    if (o >= O) return;
    float s = 0.f;
    for (int r = 0; r < nr; ++r) s += b[(long)r * O + o];
    bs[o] = s;
}

// ---------------- CSR build (once per call; reused by both layers) ----------------
__global__ void deg_count(const int* __restrict__ ei, int* __restrict__ deg) {
    int idx = blockIdx.x * blockDim.x + threadIdx.x;
    if (idx >= RR * EE) return;
    int r = idx / EE, e = idx - r * EE;
    int dst = ei[(size_t)r * 2 * EE + EE + e];
    atomicAdd(&deg[r * NN + dst], 1);
}

// one-block exclusive scan over NB entries -> off[NB+1]
__global__ __launch_bounds__(1024) void scan_offsets(const int* __restrict__ deg,
                                                     int* __restrict__ off) {
    __shared__ int sums[1024];
    int t = threadIdx.x;
    const int per = (NB + 1023) / 1024;
    int lo = t * per, hi = min(lo + per, NB);
    int s = 0;
    for (int i = lo; i < hi; ++i) s += deg[i];
    sums[t] = s;
    __syncthreads();
    for (int st = 1; st < 1024; st <<= 1) {
        int v = (t >= st) ? sums[t - st] : 0;
        __syncthreads();
        sums[t] += v;
        __syncthreads();
    }
    int excl = (t == 0) ? 0 : sums[t - 1];
    for (int i = lo; i < hi; ++i) { off[i] = excl; excl += deg[i]; }
    if (t == 1023) off[NB] = excl;
}

// cursor pre-loaded with off values; elist[pos] = src
__global__ void fill_csr(const int* __restrict__ ei, int* __restrict__ cursor,
                         int* __restrict__ elist) {
    int idx = blockIdx.x * blockDim.x + threadIdx.x;
    if (idx >= RR * EE) return;
    int r = idx / EE, e = idx - r * EE;
    int src = ei[(size_t)r * 2 * EE + e];
    int dst = ei[(size_t)r * 2 * EE + EE + e];
    int p = atomicAdd(&cursor[r * NN + dst], 1);
    elist[p] = src;
}

// ---------------- gather aggregation: one wave per (node, relation) ----------------
// agg[n][rl*D + d] = sum over in-edges of feat[src][d]
template <int D>
__global__ void gather_rows(const float* __restrict__ feat, const int* __restrict__ elist,
                            const int* __restrict__ off, float* __restrict__ agg,
                            int rbase, int chunk) {
    constexpr int V = D / 64;  // floats per lane: 2 (D=128) or 4 (D=256)
    int wv = blockIdx.x * (blockDim.x >> 6) + (threadIdx.x >> 6);
    int lane = threadIdx.x & 63;
    if (wv >= NN * chunk) return;
    int n = wv / chunk, rl = wv - n * chunk;
    int b = (rbase + rl) * NN + n;
    int beg = off[b], end = off[b + 1];
    float acc[V];
#pragma unroll
    for (int v = 0; v < V; ++v) acc[v] = 0.f;
    for (int e = beg; e < end; ++e) {
        int src = elist[e];
        const float* fp = feat + (size_t)src * D + lane * V;
        if constexpr (V == 2) {
            float2 f = *(const float2*)fp;
            acc[0] += f.x; acc[1] += f.y;
        } else {
            float4 f = *(const float4*)fp;
            acc[0] += f.x; acc[1] += f.y; acc[2] += f.z; acc[3] += f.w;
        }
    }
    float* op = agg + (size_t)n * (chunk * D) + rl * D + lane * V;
    if constexpr (V == 2) *(float2*)op = make_float2(acc[0], acc[1]);
    else *(float4*)op = make_float4(acc[0], acc[1], acc[2], acc[3]);
}

// ---------------- tiled fp32 GEMM: C[n,o] (+)= scale*(dot(A[n,:],Wt[:,o]) + bias[o]) ----
// A: [M,K] row-major, Wt: [K,256], C: [M,256]. Block: 64 rows x 256 cols, 256 threads.
#define GBM 64
#define GBK 32
__global__ __launch_bounds__(256) void gemm_acc(
    const float* __restrict__ A, int K, const float* __restrict__ Wt,
    const float* __restrict__ bias, float* __restrict__ C,
    int M, float scale, int accum) {
    __shared__ float aT[GBK][GBM + 4];  // transposed, stride 68 (16B-aligned rows)
    int n0 = blockIdx.x * GBM;
    int tid = threadIdx.x;
    int ct = tid & 63;
    int rg = tid >> 6;

    float acc[16][4];
#pragma unroll
    for (int i = 0; i < 16; ++i)
#pragma unroll
        for (int j = 0; j < 4; ++j) acc[i][j] = 0.f;

    int rr = tid >> 2;        // 0..63 row within tile
    int kk0 = (tid & 3) * 8;  // 0,8,16,24

    for (int k0 = 0; k0 < K; k0 += GBK) {
        float4 v0, v1;
        if (n0 + rr < M) {
            const float* ap = A + (size_t)(n0 + rr) * K + k0 + kk0;
            v0 = *(const float4*)ap;
            v1 = *(const float4*)(ap + 4);
        } else {
            v0 = make_float4(0.f, 0.f, 0.f, 0.f);
            v1 = v0;
        }
        __syncthreads();
        aT[kk0 + 0][rr] = v0.x; aT[kk0 + 1][rr] = v0.y;
        aT[kk0 + 2][rr] = v0.z; aT[kk0 + 3][rr] = v0.w;
        aT[kk0 + 4][rr] = v1.x; aT[kk0 + 5][rr] = v1.y;
        aT[kk0 + 6][rr] = v1.z; aT[kk0 + 7][rr] = v1.w;
        __syncthreads();
#pragma unroll
        for (int kk = 0; kk < GBK; ++kk) {
            const float* wrow = Wt + (size_t)(k0 + kk) * 256 + ct;
            float w0 = wrow[0], w1 = wrow[64], w2 = wrow[128], w3 = wrow[192];
            const float* arow = &aT[kk][rg * 16];
            float4 a0 = *(const float4*)(arow);
            float4 a1 = *(const float4*)(arow + 4);
            float4 a2 = *(const float4*)(arow + 8);
            float4 a3 = *(const float4*)(arow + 12);
            float av[16] = {a0.x, a0.y, a0.z, a0.w, a1.x, a1.y, a1.z, a1.w,
                            a2.x, a2.y, a2.z, a2.w, a3.x, a3.y, a3.z, a3.w};
#pragma unroll
            for (int i = 0; i < 16; ++i) {
                acc[i][0] += av[i] * w0;
                acc[i][1] += av[i] * w1;
                acc[i][2] += av[i] * w2;
                acc[i][3] += av[i] * w3;
            }
        }
        __syncthreads();
    }

    int rbase = n0 + rg * 16;
#pragma unroll
    for (int i = 0; i < 16; ++i) {
        int n = rbase + i;
        if (n >= M) break;
#pragma unroll
        for (int j = 0; j < 4; ++j) {
            int o = ct + 64 * j;
            float v = acc[i][j];
            if (bias) v += bias[o];
            v *= scale;
            size_t idx = (size_t)n * 256 + o;
            if (accum) C[idx] += v;
            else C[idx] = v;
        }
    }
}

// ---------------- l2-normalize + relu, in place, one wave per row ----------------
__global__ void norm_relu(float* __restrict__ H, int M) {
    int row = blockIdx.x * 4 + (threadIdx.x >> 6);
    if (row >= M) return;
    int lane = threadIdx.x & 63;
    float4* p = (float4*)(H + (size_t)row * 256);
    float4 v = p[lane];
    float ss = v.x * v.x + v.y * v.y + v.z * v.z + v.w * v.w;
    for (int off = 1; off < 64; off <<= 1) ss += __shfl_xor(ss, off);
    float inv = 1.0f / fmaxf(sqrtf(ss), 1e-12f);
    v.x = fmaxf(v.x * inv, 0.f);
    v.y = fmaxf(v.y * inv, 0.f);
    v.z = fmaxf(v.z * inv, 0.f);
    v.w = fmaxf(v.w * inv, 0.f);
    p[lane] = v;
}

extern "C" void kernel_launch(void* const* d_in, const int* in_sizes, int n_in,
                              void* d_out, int out_size, void* d_ws, size_t ws_size,
                              hipStream_t stream) {
    const float* x   = (const float*)d_in[0];
    const int*   ei  = (const int*)d_in[1];
    const float* W1n = (const float*)d_in[2];
    const float* b1  = (const float*)d_in[3];
    const float* W1r = (const float*)d_in[4];
    const float* W2n = (const float*)d_in[5];
    const float* b2  = (const float*)d_in[6];
    const float* W2r = (const float*)d_in[7];
    float* out = (float*)d_out;

    // ---- workspace layout ----
    float* ws = (float*)d_ws;
    float* HBUF   = ws;                                  // NN*256 f32
    int*   degc   = (int*)(HBUF + (size_t)NN * 256);     // NB  (deg, then cursor)
    int*   off    = degc + NB;                           // NB+1
    int*   elist  = off + NB + 3;                        // RR*EE
    float* w1n_t  = (float*)(elist + (size_t)RR * EE);   // 4*128*256 (stacked [r*128+k][o])
    float* w1rs_t = w1n_t + 4 * 128 * 256;               // 128*256
    float* w2n_t  = w1rs_t + 128 * 256;                  // 4*256*256 (stacked)
    float* w2rs_t = w2n_t + 4 * 256 * 256;               // 256*256
    float* b1s    = w2rs_t + 256 * 256;                  // 256
    float* b2s    = b1s + 256;                           // 256
    float* AGG    = b2s + 256 + 64;                      // remainder

    size_t used_f  = (size_t)(AGG - ws);
    size_t avail_f = (ws_size / 4 > used_f) ? ws_size / 4 - used_f : 0;
    int c2 = (avail_f >= (size_t)NN * 4 * 256) ? 4 : (avail_f >= (size_t)NN * 2 * 256) ? 2 : 1;
    int c1 = (avail_f >= (size_t)NN * 4 * 128) ? 4 : (avail_f >= (size_t)NN * 2 * 128) ? 2 : 1;

    // ---- CSR build (shared by both layers) ----
    hipMemsetAsync(degc, 0, (size_t)NB * sizeof(int), stream);
    {
        int nE = RR * EE;
        deg_count<<<(nE + 255) / 256, 256, 0, stream>>>(ei, degc);
        scan_offsets<<<1, 1024, 0, stream>>>(degc, off);
        hipMemcpyAsync(degc, off, (size_t)NB * sizeof(int), hipMemcpyDeviceToDevice, stream);
        fill_csr<<<(nE + 255) / 256, 256, 0, stream>>>(ei, degc, elist);
    }

    // ---- weight prep ----
    {
        int nw1 = 128 * 256, nw2 = 256 * 256;
        for (int r = 0; r < RR; ++r)
            transpose_sum<<<(nw1 + 255) / 256, 256, 0, stream>>>(
                W1n + (size_t)r * DOUT * DIN, w1n_t + (size_t)r * 128 * 256, 128, 256, 1, 0);
        transpose_sum<<<(nw1 + 255) / 256, 256, 0, stream>>>(
            W1r, w1rs_t, 128, 256, RR, (long)DOUT * DIN);
        for (int r = 0; r < RR; ++r)
            transpose_sum<<<(nw2 + 255) / 256, 256, 0, stream>>>(
                W2n + (size_t)r * DOUT * DOUT, w2n_t + (size_t)r * 256 * 256, 256, 256, 1, 0);
        transpose_sum<<<(nw2 + 255) / 256, 256, 0, stream>>>(
            W2r, w2rs_t, 256, 256, RR, (long)DOUT * DOUT);
        bias_sum<<<1, 256, 0, stream>>>(b1, b1s, 256, RR);
        bias_sum<<<1, 256, 0, stream>>>(b2, b2s, 256, RR);
    }

    int gemm_grid = (NN + GBM - 1) / GBM;
    const float scale = 1.0f / RR;

    // ---- layer 1 ----
    gemm_acc<<<gemm_grid, 256, 0, stream>>>(x, 128, w1rs_t, b1s, HBUF, NN, scale, 0);
    for (int rb = 0; rb < RR; rb += c1) {
        int c = (RR - rb < c1) ? RR - rb : c1;
        gather_rows<128><<<(NN * c + 3) / 4, 256, 0, stream>>>(x, elist, off, AGG, rb, c);
        gemm_acc<<<gemm_grid, 256, 0, stream>>>(AGG, c * 128, w1n_t + (size_t)rb * 128 * 256,
                                                nullptr, HBUF, NN, scale, 1);
    }
    norm_relu<<<(NN + 3) / 4, 256, 0, stream>>>(HBUF, NN);

    // ---- layer 2 ----
    gemm_acc<<<gemm_grid, 256, 0, stream>>>(HBUF, 256, w2rs_t, b2s, out, NN, scale, 0);
    for (int rb = 0; rb < RR; rb += c2) {
        int c = (RR - rb < c2) ? RR - rb : c2;
        gather_rows<256><<<(NN * c + 3) / 4, 256, 0, stream>>>(HBUF, elist, off, AGG, rb, c);
        gemm_acc<<<gemm_grid, 256, 0, stream>>>(AGG, c * 256, w2n_t + (size_t)rb * 256 * 256,
                                                nullptr, out, NN, scale, 1);
    }
}

// Round 3
// 1295.837 us; speedup vs baseline: 3.8440x; 2.4805x over previous
//
#include <hip/hip_runtime.h>
#include <hip/hip_bf16.h>

#define NN 100000
#define DIN 128
#define DOUT 256
#define RR 4
#define EE 600000
#define NB (RR * NN)
#define SCAN_BLKS 400
#define SCAN_CHUNK 1000

typedef __attribute__((ext_vector_type(4))) float f32x4;
typedef __attribute__((ext_vector_type(8))) short short8;

__device__ __forceinline__ float bf2f(ushort u) {
    union { unsigned int i; float f; } v; v.i = ((unsigned int)u) << 16; return v.f;
}
__device__ __forceinline__ ushort f2bf(float f) {
    union { float f; unsigned int i; } v; v.f = f;
    unsigned int r = v.i + 0x7fff + ((v.i >> 16) & 1);  // RNE
    return (ushort)(r >> 16);
}

__device__ __forceinline__ void ld_g2l16(const void* g, void* l) {
    __builtin_amdgcn_global_load_lds(
        (const __attribute__((address_space(1))) void*)g,
        (__attribute__((address_space(3))) void*)l, 16, 0, 0);
}

// ---------------- weight prep: out[(kd/64)*256*64 + o*64 + kd%64] = sum_r in[r][o][k], bf16
__global__ void wprep(const float* __restrict__ in, ushort* __restrict__ out,
                      int K, int nsum, long sumstride, int kbase) {
    int idx = blockIdx.x * blockDim.x + threadIdx.x;
    if (idx >= K * 256) return;
    int k = idx >> 8, o = idx & 255;
    float s = 0.f;
    for (int r = 0; r < nsum; ++r) s += in[r * sumstride + (long)o * K + k];
    int kd = kbase + k;
    out[((size_t)(kd >> 6) * 256 + o) * 64 + (kd & 63)] = f2bf(s);
}

__global__ void bias_sum(const float* __restrict__ b, float* __restrict__ bs, int O, int nr) {
    int o = blockIdx.x * blockDim.x + threadIdx.x;
    if (o >= O) return;
    float s = 0.f;
    for (int r = 0; r < nr; ++r) s += b[(long)r * O + o];
    bs[o] = s;
}

// ---------------- CSR build ----------------
__global__ void deg_count(const int* __restrict__ ei, int* __restrict__ deg) {
    int idx = blockIdx.x * blockDim.x + threadIdx.x;
    if (idx >= RR * EE) return;
    int r = idx / EE, e = idx - r * EE;
    int dst = ei[(size_t)r * 2 * EE + EE + e];
    atomicAdd(&deg[r * NN + dst], 1);
}

__global__ __launch_bounds__(256) void scan_part(const int* __restrict__ deg,
                                                 int* __restrict__ bsum) {
    int b = blockIdx.x, t = threadIdx.x;
    int s = 0;
    for (int i = t; i < SCAN_CHUNK; i += 256) s += deg[b * SCAN_CHUNK + i];
    for (int o = 32; o > 0; o >>= 1) s += __shfl_down(s, o);
    __shared__ int red[4];
    if ((t & 63) == 0) red[t >> 6] = s;
    __syncthreads();
    if (t == 0) bsum[b] = red[0] + red[1] + red[2] + red[3];
}

__global__ __launch_bounds__(512) void scan_top(int* __restrict__ bsum) {
    __shared__ int v[512];
    int t = threadIdx.x;
    v[t] = (t < SCAN_BLKS) ? bsum[t] : 0;
    __syncthreads();
    for (int st = 1; st < 512; st <<= 1) {
        int tmp = (t >= st) ? v[t - st] : 0;
        __syncthreads();
        v[t] += tmp;
        __syncthreads();
    }
    if (t < SCAN_BLKS) bsum[t] = (t == 0) ? 0 : v[t - 1];  // exclusive
}

__global__ __launch_bounds__(256) void scan_final(const int* __restrict__ deg,
                                                  const int* __restrict__ bsum,
                                                  int* __restrict__ off) {
    __shared__ int lv[1024];
    __shared__ int ts[256];
    int b = blockIdx.x, t = threadIdx.x;
    for (int i = t; i < 1024; i += 256)
        lv[i] = (i < SCAN_CHUNK) ? deg[b * SCAN_CHUNK + i] : 0;
    __syncthreads();
    int i0 = t * 4;
    int v0 = lv[i0], v1 = lv[i0 + 1], v2 = lv[i0 + 2], v3 = lv[i0 + 3];
    ts[t] = v0 + v1 + v2 + v3;
    __syncthreads();
    for (int st = 1; st < 256; st <<= 1) {
        int tmp = (t >= st) ? ts[t - st] : 0;
        __syncthreads();
        ts[t] += tmp;
        __syncthreads();
    }
    int run = bsum[b] + (t ? ts[t - 1] : 0);
    if (i0 < SCAN_CHUNK) {
        off[b * SCAN_CHUNK + i0 + 0] = run; run += v0;
        off[b * SCAN_CHUNK + i0 + 1] = run; run += v1;
        off[b * SCAN_CHUNK + i0 + 2] = run; run += v2;
        off[b * SCAN_CHUNK + i0 + 3] = run; run += v3;
    }
    if (b == SCAN_BLKS - 1 && t == 255) off[NB] = bsum[b] + ts[255];
}

__global__ void fill_csr(const int* __restrict__ ei, int* __restrict__ cursor,
                         int* __restrict__ elist) {
    int idx = blockIdx.x * blockDim.x + threadIdx.x;
    if (idx >= RR * EE) return;
    int r = idx / EE, e = idx - r * EE;
    int src = ei[(size_t)r * 2 * EE + e];
    int dst = ei[(size_t)r * 2 * EE + EE + e];
    int p = atomicAdd(&cursor[r * NN + dst], 1);
    elist[p] = src;
}

// ---------------- fp32 x -> bf16 into A1 cols 0..127 ----------------
__global__ void cvt_x(const float* __restrict__ x, ushort* __restrict__ A1, int s1) {
    int t = blockIdx.x * blockDim.x + threadIdx.x;
    if (t >= NN * 32) return;
    int n = t >> 5, c4 = (t & 31) * 4;
    float4 v = *(const float4*)&x[(size_t)n * 128 + c4];
    ushort4 o = {f2bf(v.x), f2bf(v.y), f2bf(v.z), f2bf(v.w)};
    *(ushort4*)&A1[(size_t)n * s1 + c4] = o;
}

// ---------------- l2norm + relu: read fp32 H, write bf16 into A2 cols 0..255 ----------------
__global__ void norm_relu_cvt(const float* __restrict__ H, ushort* __restrict__ A2,
                              int s2, int M) {
    int row = blockIdx.x * 4 + (threadIdx.x >> 6);
    if (row >= M) return;
    int lane = threadIdx.x & 63;
    float4 v = ((const float4*)(H + (size_t)row * 256))[lane];
    float ss = v.x * v.x + v.y * v.y + v.z * v.z + v.w * v.w;
    for (int off = 1; off < 64; off <<= 1) ss += __shfl_xor(ss, off);
    float inv = 1.0f / fmaxf(sqrtf(ss), 1e-12f);
    ushort4 o = {f2bf(fmaxf(v.x * inv, 0.f)), f2bf(fmaxf(v.y * inv, 0.f)),
                 f2bf(fmaxf(v.z * inv, 0.f)), f2bf(fmaxf(v.w * inv, 0.f))};
    *(ushort4*)&A2[(size_t)row * s2 + lane * 4] = o;
}

// ---------------- gather aggregation (bf16 in, fp32 acc, bf16 out) ----------------
template <int D>
__global__ void gather_bf16(const ushort* __restrict__ feat, int sfeat,
                            const int* __restrict__ elist, const int* __restrict__ off,
                            ushort* __restrict__ agg, int sout, int rbase, int chunk) {
    constexpr int V = D / 64;  // ushorts per lane: 2 (D=128) or 4 (D=256)
    int wv = blockIdx.x * 4 + (threadIdx.x >> 6);
    int lane = threadIdx.x & 63;
    if (wv >= NN * chunk) return;
    int n = wv / chunk, rl = wv - n * chunk;
    int b = (rbase + rl) * NN + n;
    int beg = off[b], end = off[b + 1];
    float acc[V];
#pragma unroll
    for (int v = 0; v < V; ++v) acc[v] = 0.f;
    for (int e = beg; e < end; ++e) {
        int src = elist[e];
        const ushort* fp = feat + (size_t)src * sfeat + lane * V;
        if constexpr (V == 2) {
            ushort2 u = *(const ushort2*)fp;
            acc[0] += bf2f(u.x); acc[1] += bf2f(u.y);
        } else {
            ushort4 u = *(const ushort4*)fp;
            acc[0] += bf2f(u.x); acc[1] += bf2f(u.y);
            acc[2] += bf2f(u.z); acc[3] += bf2f(u.w);
        }
    }
    ushort* op = agg + (size_t)n * sout + rl * D + lane * V;
    if constexpr (V == 2) {
        ushort2 o = {f2bf(acc[0]), f2bf(acc[1])};
        *(ushort2*)op = o;
    } else {
        ushort4 o = {f2bf(acc[0]), f2bf(acc[1]), f2bf(acc[2]), f2bf(acc[3])};
        *(ushort4*)op = o;
    }
}

// ---------------- bf16 MFMA GEMM: C[M,256] (+)= scale*(A[M,K]·W + bias) ----------------
// A: bf16 [M rows, lda stride]; W: bf16 MFMA layout [K/64][256][64]; C fp32.
// Block: 256 threads (4 waves), tile 128 rows x 256 cols; wave = 64x128 quadrant.
__global__ __launch_bounds__(256) void gemm_mfma(
    const ushort* __restrict__ A, int lda, int K,
    const ushort* __restrict__ W, const float* __restrict__ bias,
    float* __restrict__ C, int M, float scale, int accum) {
    __shared__ ushort lA[128 * 64];  // [row][k] 16KB
    __shared__ ushort lB[256 * 64];  // [col][k] 32KB
    const int tid = threadIdx.x;
    const int w = tid >> 6, lane = tid & 63;
    const int wr = w >> 1, wc = w & 1;
    const int row0 = blockIdx.x * 128;

    f32x4 acc[4][8];
#pragma unroll
    for (int i = 0; i < 4; ++i)
#pragma unroll
        for (int j = 0; j < 8; ++j) acc[i][j] = {0.f, 0.f, 0.f, 0.f};

    const int arow = lane >> 3;        // 0..7
    const int acol = (lane & 7) * 8;   // bf16 col offset within 64

    for (int k0 = 0; k0 < K; k0 += 64) {
        __syncthreads();  // previous iter's LDS reads complete
#pragma unroll
        for (int c = 0; c < 4; ++c) {
            int r = w * 32 + c * 8 + arow;
            const ushort* g = A + (size_t)(row0 + r) * lda + k0 + acol;
            ld_g2l16(g, &lA[r * 64 + acol]);
        }
        const ushort* wb = W + (size_t)(k0 >> 6) * (256 * 64);
#pragma unroll
        for (int c = 0; c < 8; ++c) {
            int o = (w * 8 + c) * 512 + lane * 8;
            ld_g2l16(wb + o, &lB[o]);
        }
        asm volatile("s_waitcnt vmcnt(0)" ::: "memory");
        __syncthreads();
#pragma unroll
        for (int ks = 0; ks < 2; ++ks) {
            const int ko = ks * 32 + (lane >> 4) * 8;
            short8 af[4];
#pragma unroll
            for (int rf = 0; rf < 4; ++rf)
                af[rf] = *(const short8*)&lA[(wr * 64 + rf * 16 + (lane & 15)) * 64 + ko];
#pragma unroll
            for (int cf = 0; cf < 8; ++cf) {
                short8 bfrag = *(const short8*)&lB[(wc * 128 + cf * 16 + (lane & 15)) * 64 + ko];
#pragma unroll
                for (int rf = 0; rf < 4; ++rf)
                    acc[rf][cf] = __builtin_amdgcn_mfma_f32_16x16x32_bf16(
                        af[rf], bfrag, acc[rf][cf], 0, 0, 0);
            }
        }
    }

    const int rb0 = row0 + wr * 64 + (lane >> 4) * 4;
    const int cb0 = wc * 128 + (lane & 15);
#pragma unroll
    for (int rf = 0; rf < 4; ++rf) {
#pragma unroll
        for (int cf = 0; cf < 8; ++cf) {
            int col = cb0 + cf * 16;
            float badd = bias ? bias[col] : 0.f;
#pragma unroll
            for (int m = 0; m < 4; ++m) {
                int r = rb0 + rf * 16 + m;
                if (r < M) {
                    float v = (acc[rf][cf][m] + badd) * scale;
                    size_t idx = (size_t)r * 256 + col;
                    if (accum) C[idx] += v;
                    else C[idx] = v;
                }
            }
        }
    }
}

extern "C" void kernel_launch(void* const* d_in, const int* in_sizes, int n_in,
                              void* d_out, int out_size, void* d_ws, size_t ws_size,
                              hipStream_t stream) {
    const float* x   = (const float*)d_in[0];
    const int*   ei  = (const int*)d_in[1];
    const float* W1n = (const float*)d_in[2];
    const float* b1  = (const float*)d_in[3];
    const float* W1r = (const float*)d_in[4];
    const float* W2n = (const float*)d_in[5];
    const float* b2  = (const float*)d_in[6];
    const float* W2r = (const float*)d_in[7];
    float* outf = (float*)d_out;  // also used as fp32 h buffer between GEMM1 and norm

    // ---- choose relation-chunking by ws budget ----
    const size_t fixedB = (size_t)4 * RR * EE    // elist
                        + (size_t)4 * NB         // degc/cursor
                        + (size_t)4 * (NB + 1)   // off
                        + 4 * 512                // bsum
                        + 2ull * 640 * 256       // W1c
                        + 2ull * 1280 * 256      // W2c
                        + 4 * 512 + 1024;        // biases + align slack
    int c1 = 1, c2 = 1;
    for (int t2 : {4, 2, 1})
        for (int t1 : {4, 2, 1}) {
            size_t need = fixedB + 2ull * NN * 128 * (1 + t1) + 2ull * NN * 256 * (1 + t2);
            if (need <= ws_size && (t2 > c2 || (t2 == c2 && t1 > c1))) { c1 = t1; c2 = t2; }
        }
    const int s1 = 128 * (1 + c1);
    const int s2 = 256 * (1 + c2);

    // ---- ws layout (A1/A2 first; elist after A2 absorbs last-tile staging overshoot) ----
    ushort* A1   = (ushort*)d_ws;                      // NN*s1
    ushort* A2   = A1 + (size_t)NN * s1;               // NN*s2
    int*   elist = (int*)(A2 + (size_t)NN * s2);       // RR*EE
    int*   degc  = elist + (size_t)RR * EE;            // NB
    int*   off   = degc + NB;                          // NB+1
    int*   bsum  = off + NB + 1;                       // 512
    ushort* W1c  = (ushort*)(bsum + 512);              // 640*256
    ushort* W2c  = W1c + 640 * 256;                    // 1280*256
    float* b1s   = (float*)(W2c + 1280 * 256);
    float* b2s   = b1s + 256;

    const float scale = 1.0f / RR;
    const int nE = RR * EE;

    // ---- CSR build ----
    hipMemsetAsync(degc, 0, (size_t)NB * sizeof(int), stream);
    deg_count<<<(nE + 255) / 256, 256, 0, stream>>>(ei, degc);
    scan_part<<<SCAN_BLKS, 256, 0, stream>>>(degc, bsum);
    scan_top<<<1, 512, 0, stream>>>(bsum);
    scan_final<<<SCAN_BLKS, 256, 0, stream>>>(degc, bsum, off);
    hipMemcpyAsync(degc, off, (size_t)NB * sizeof(int), hipMemcpyDeviceToDevice, stream);
    fill_csr<<<(nE + 255) / 256, 256, 0, stream>>>(ei, degc, elist);

    // ---- weight prep (bf16, MFMA layout) ----
    wprep<<<128, 256, 0, stream>>>(W1r, W1c, 128, RR, (long)DOUT * DIN, 0);
    for (int r = 0; r < RR; ++r)
        wprep<<<128, 256, 0, stream>>>(W1n + (size_t)r * DOUT * DIN, W1c, 128, 1, 0,
                                       128 + r * 128);
    wprep<<<256, 256, 0, stream>>>(W2r, W2c, 256, RR, (long)DOUT * DOUT, 0);
    for (int r = 0; r < RR; ++r)
        wprep<<<256, 256, 0, stream>>>(W2n + (size_t)r * DOUT * DOUT, W2c, 256, 1, 0,
                                       256 + r * 256);
    bias_sum<<<1, 256, 0, stream>>>(b1, b1s, 256, RR);
    bias_sum<<<1, 256, 0, stream>>>(b2, b2s, 256, RR);

    cvt_x<<<(NN * 32 + 255) / 256, 256, 0, stream>>>(x, A1, s1);

    const int ggrid = (NN + 127) / 128;

    // ---- layer 1: h(fp32, in d_out) = scale*(A1·W1c + b1s) ----
    {
        gather_bf16<128><<<(NN * c1 + 3) / 4, 256, 0, stream>>>(
            A1, s1, elist, off, A1 + 128, s1, 0, c1);
        gemm_mfma<<<ggrid, 256, 0, stream>>>(A1, s1, 128 + c1 * 128, W1c, b1s,
                                             outf, NN, scale, 0);
        for (int rb = c1; rb < RR; rb += c1) {
            int c = (RR - rb < c1) ? RR - rb : c1;
            gather_bf16<128><<<(NN * c + 3) / 4, 256, 0, stream>>>(
                A1, s1, elist, off, A1 + 128, s1, rb, c);
            gemm_mfma<<<ggrid, 256, 0, stream>>>(
                A1 + 128, s1, c * 128, W1c + (size_t)(2 + 2 * rb) * 256 * 64,
                nullptr, outf, NN, scale, 1);
        }
    }

    norm_relu_cvt<<<(NN + 3) / 4, 256, 0, stream>>>(outf, A2, s2, NN);

    // ---- layer 2: out = scale*(A2·W2c + b2s) ----
    {
        gather_bf16<256><<<(NN * c2 + 3) / 4, 256, 0, stream>>>(
            A2, s2, elist, off, A2 + 256, s2, 0, c2);
        gemm_mfma<<<ggrid, 256, 0, stream>>>(A2, s2, 256 + c2 * 256, W2c, b2s,
                                             outf, NN, scale, 0);
        for (int rb = c2; rb < RR; rb += c2) {
            int c = (RR - rb < c2) ? RR - rb : c2;
            gather_bf16<256><<<(NN * c + 3) / 4, 256, 0, stream>>>(
                A2, s2, elist, off, A2 + 256, s2, rb, c);
            gemm_mfma<<<ggrid, 256, 0, stream>>>(
                A2 + 256, s2, c * 256, W2c + (size_t)(4 + 4 * rb) * 256 * 64,
                nullptr, outf, NN, scale, 1);
        }
    }
}